// Round 4
// baseline (958.509 us; speedup 1.0000x reference)
//
#include <hip/hip_runtime.h>

#define HIDDEN 128
#define OUT_EMB 256
#define NLAYERS 3
#define TM 64

typedef __bf16 bf16x8 __attribute__((ext_vector_type(8)));
typedef float f32x4 __attribute__((ext_vector_type(4)));

__device__ __forceinline__ unsigned short f2bf(float x) {
    union { float f; unsigned u; } c; c.f = x;
    unsigned r = c.u + 0x7fff + ((c.u >> 16) & 1);
    return (unsigned short)(r >> 16);
}
__device__ __forceinline__ float bf2f(unsigned short h) {
    union { unsigned u; float f; } c; c.u = ((unsigned)h) << 16;
    return c.f;
}

// ---------------- CSR build ----------------
__global__ __launch_bounds__(256) void hist_kernel(
    const int* __restrict__ idx, int* __restrict__ counts, int ne)
{
    int e = blockIdx.x * 256 + threadIdx.x;
    if (e < ne) atomicAdd(&counts[idx[e]], 1);
}

__global__ __launch_bounds__(256) void scan1_kernel(
    const int* __restrict__ counts, int* __restrict__ bsum, int n)
{
    __shared__ int sh[256];
    int t = threadIdx.x;
    int i = blockIdx.x * 256 + t;
    sh[t] = (i < n) ? counts[i] : 0;
    __syncthreads();
    for (int off = 128; off > 0; off >>= 1) {
        if (t < off) sh[t] += sh[t + off];
        __syncthreads();
    }
    if (t == 0) bsum[blockIdx.x] = sh[0];
}

__global__ __launch_bounds__(256) void scan2_kernel(
    int* __restrict__ bsum, int* __restrict__ boff, int nb)
{
    __shared__ int sh[256];
    int t = threadIdx.x;
    int v = (t < nb) ? bsum[t] : 0;
    sh[t] = v;
    __syncthreads();
    for (int off = 1; off < 256; off <<= 1) {
        int u = (t >= off) ? sh[t - off] : 0;
        __syncthreads();
        sh[t] += u;
        __syncthreads();
    }
    if (t < nb) boff[t] = sh[t] - v;
}

__global__ __launch_bounds__(256) void scan3_kernel(
    const int* __restrict__ counts, const int* __restrict__ boff,
    int* __restrict__ offsets, int* __restrict__ cursor, int n)
{
    __shared__ int sh[256];
    int t = threadIdx.x;
    int i = blockIdx.x * 256 + t;
    int v = (i < n) ? counts[i] : 0;
    sh[t] = v;
    __syncthreads();
    for (int off = 1; off < 256; off <<= 1) {
        int u = (t >= off) ? sh[t - off] : 0;
        __syncthreads();
        sh[t] += u;
        __syncthreads();
    }
    if (i < n) {
        int excl = boff[blockIdx.x] + sh[t] - v;
        offsets[i] = excl;
        cursor[i]  = excl;
    }
}

__global__ __launch_bounds__(256) void fill_kernel(
    const int* __restrict__ idx, int* __restrict__ cursor,
    int* __restrict__ edge_list, int ne)
{
    int e = blockIdx.x * 256 + threadIdx.x;
    if (e < ne) {
        int pos = atomicAdd(&cursor[idx[e]], 1);
        edge_list[pos] = e;
    }
}

// ---------------- gather-reduce (unchanged from R3) ----------------
__global__ __launch_bounds__(256) void gather_kernel(
    const float* __restrict__ e2, const int* __restrict__ edge_list,
    const int* __restrict__ offsets, const int* __restrict__ counts,
    unsigned short* __restrict__ vbf, int Mpad)
{
    int node = blockIdx.x * 4 + (threadIdx.x >> 6);
    if (node >= Mpad) return;
    int lane = threadIdx.x & 63;
    int half = lane >> 5;
    int c4   = lane & 31;
    int start = offsets[node];
    int cnt   = counts[node];

    f32x4 a0 = {0.f, 0.f, 0.f, 0.f};
    f32x4 a1 = {0.f, 0.f, 0.f, 0.f};

    int j = 0;
    for (; j + 4 <= cnt; j += 4) {
        int e0 = edge_list[start + j + half];
        int e1 = edge_list[start + j + 2 + half];
        f32x4 x0 = *(const f32x4*)(e2 + (long long)e0 * HIDDEN + c4 * 4);
        f32x4 x1 = *(const f32x4*)(e2 + (long long)e1 * HIDDEN + c4 * 4);
        a0 += x0;
        a1 += x1;
    }
    for (; j + 2 <= cnt; j += 2) {
        int e0 = edge_list[start + j + half];
        f32x4 x0 = *(const f32x4*)(e2 + (long long)e0 * HIDDEN + c4 * 4);
        a0 += x0;
    }
    if (j < cnt && half == 0) {
        int e0 = edge_list[start + j];
        f32x4 x0 = *(const f32x4*)(e2 + (long long)e0 * HIDDEN + c4 * 4);
        a1 += x0;
    }
    a0 += a1;
    a0[0] += __shfl_xor(a0[0], 32);
    a0[1] += __shfl_xor(a0[1], 32);
    a0[2] += __shfl_xor(a0[2], 32);
    a0[3] += __shfl_xor(a0[3], 32);

    if (half == 0) {
        unsigned lo = (unsigned)f2bf(a0[0]) | ((unsigned)f2bf(a0[1]) << 16);
        unsigned hi = (unsigned)f2bf(a0[2]) | ((unsigned)f2bf(a0[3]) << 16);
        uint2 p; p.x = lo; p.y = hi;
        *(uint2*)(vbf + (long long)node * HIDDEN + c4 * 4) = p;
    }
}

// ---------------- weight fp32 -> bf16 ----------------
__global__ __launch_bounds__(256) void convert_kernel(
    const float* __restrict__ wup_f, const float* __restrict__ ws_f,
    unsigned short* __restrict__ wup, unsigned short* __restrict__ wsl)
{
    int t = blockIdx.x * blockDim.x + threadIdx.x;
    const int n1 = OUT_EMB * HIDDEN;
    const int n2 = NLAYERS * OUT_EMB * OUT_EMB;
    if (t < n1) wup[t] = f2bf(wup_f[t]);
    else if (t < n1 + n2) wsl[t - n1] = f2bf(ws_f[t - n1]);
}

// ---------------- layer GEMM sweep ----------------
// C[M,256] = act(A[M,K] @ W[256,K]^T + bias), optional SiLU.
// block = 64 rows x full 256 cols; wave wv owns cols [wv*64, wv*64+64).
// No LDS, no barriers. A read from global (all 4 waves same rows -> L1 hit);
// W is L2-resident (<=128 KB/layer) and reused across all 782 blocks.
template<int K, bool SILU>
__global__ __launch_bounds__(256) void gemm_kernel(
    const unsigned short* __restrict__ A,   // [Mpad][K] bf16
    const unsigned short* __restrict__ W,   // [256][K]  bf16
    const float* __restrict__ bias,         // [256]
    unsigned short* __restrict__ C,         // [Mpad][256] bf16
    int Mpad)
{
    const int tid  = threadIdx.x;
    const int wv   = tid >> 6;
    const int lane = tid & 63;
    const int ln15 = lane & 15;
    const int kq   = lane >> 4;
    const int n0   = wv * 64;
    const long long rowbase = (long long)blockIdx.x * TM;

    f32x4 acc[4][4];
    #pragma unroll
    for (int mt = 0; mt < 4; ++mt)
        #pragma unroll
        for (int nt = 0; nt < 4; ++nt)
            acc[mt][nt] = (f32x4){0.f, 0.f, 0.f, 0.f};

    const unsigned short* Abase = A + rowbase * K + ln15 * K + kq * 8;
    const unsigned short* Wbase = W + (n0 + ln15) * K + kq * 8;

    #pragma unroll
    for (int ks = 0; ks < K / 32; ++ks) {
        bf16x8 a[4], b[4];
        #pragma unroll
        for (int mt = 0; mt < 4; ++mt)
            a[mt] = *(const bf16x8*)(Abase + (mt * 16) * K + ks * 32);
        #pragma unroll
        for (int nt = 0; nt < 4; ++nt)
            b[nt] = *(const bf16x8*)(Wbase + (nt * 16) * K + ks * 32);
        #pragma unroll
        for (int mt = 0; mt < 4; ++mt)
            #pragma unroll
            for (int nt = 0; nt < 4; ++nt)
                acc[mt][nt] = __builtin_amdgcn_mfma_f32_16x16x32_bf16(a[mt], b[nt], acc[mt][nt], 0, 0, 0);
    }

    #pragma unroll
    for (int nt = 0; nt < 4; ++nt) {
        int n = n0 + nt * 16 + ln15;
        float bi = bias[n];
        #pragma unroll
        for (int mt = 0; mt < 4; ++mt)
            #pragma unroll
            for (int r = 0; r < 4; ++r) {
                float x = acc[mt][nt][r] + bi;
                if (SILU) x = x / (1.f + __expf(-x));
                long long row = rowbase + mt * 16 + kq * 4 + r;
                C[row * OUT_EMB + n] = f2bf(x);
            }
    }
}

// ---------------- output projection: out[m] = act[m] . wout ----------------
__global__ __launch_bounds__(256) void out_kernel(
    const unsigned short* __restrict__ A, const float* __restrict__ wout,
    float* __restrict__ out, int M)
{
    int t = blockIdx.x * 256 + threadIdx.x;
    int r = t >> 2;
    int part = t & 3;
    if (r >= M) return;
    const unsigned short* arow = A + (long long)r * OUT_EMB + part * 64;
    const float* wrow = wout + part * 64;
    float s = 0.f;
    #pragma unroll
    for (int j = 0; j < 64; ++j) s += bf2f(arow[j]) * wrow[j];
    s += __shfl_xor(s, 1);
    s += __shfl_xor(s, 2);
    if (part == 0) out[r] = s;
}

extern "C" void kernel_launch(void* const* d_in, const int* in_sizes, int n_in,
                              void* d_out, int out_size, void* d_ws, size_t ws_size,
                              hipStream_t stream) {
    const float* e2    = (const float*)d_in[0];
    const int*   idx   = (const int*)d_in[1];
    const float* W_up  = (const float*)d_in[2];
    const float* b_up  = (const float*)d_in[3];
    const float* Ws    = (const float*)d_in[4];
    const float* bs    = (const float*)d_in[5];
    const float* W_out = (const float*)d_in[6];

    const int ne = in_sizes[0] / HIDDEN;
    const int M  = out_size;                      // 50000
    const int Mpad = ((M + TM - 1) / TM) * TM;    // 50048
    const int nb = (Mpad + 255) / 256;            // 196

    char* p = (char*)d_ws;
    unsigned short* vbf    = (unsigned short*)p;  p += (size_t)Mpad * HIDDEN * 2;
    unsigned short* wup_bf = (unsigned short*)p;  p += (size_t)OUT_EMB * HIDDEN * 2;
    unsigned short* wsl_bf = (unsigned short*)p;  p += (size_t)NLAYERS * OUT_EMB * OUT_EMB * 2;
    unsigned short* actA   = (unsigned short*)p;  p += (size_t)Mpad * OUT_EMB * 2;
    unsigned short* actB   = (unsigned short*)p;  p += (size_t)Mpad * OUT_EMB * 2;
    int* counts    = (int*)p;  p += (size_t)Mpad * 4;
    int* offsets   = (int*)p;  p += (size_t)Mpad * 4;
    int* cursor    = (int*)p;  p += (size_t)Mpad * 4;
    int* bsum      = (int*)p;  p += 256 * 4;
    int* boff      = (int*)p;  p += 256 * 4;
    int* edge_list = (int*)p;  p += (size_t)ne * 4;

    hipMemsetAsync(counts, 0, (size_t)Mpad * 4, stream);

    hist_kernel <<<(ne + 255) / 256, 256, 0, stream>>>(idx, counts, ne);
    scan1_kernel<<<nb, 256, 0, stream>>>(counts, bsum, Mpad);
    scan2_kernel<<<1, 256, 0, stream>>>(bsum, boff, nb);
    scan3_kernel<<<nb, 256, 0, stream>>>(counts, boff, offsets, cursor, Mpad);
    fill_kernel <<<(ne + 255) / 256, 256, 0, stream>>>(idx, cursor, edge_list, ne);

    {
        int total = OUT_EMB * HIDDEN + NLAYERS * OUT_EMB * OUT_EMB;
        convert_kernel<<<(total + 255) / 256, 256, 0, stream>>>(W_up, Ws, wup_bf, wsl_bf);
    }

    gather_kernel<<<(Mpad + 3) / 4, 256, 0, stream>>>(e2, edge_list, offsets, counts, vbf, Mpad);

    const int gblocks = Mpad / TM;  // 782
    gemm_kernel<HIDDEN, false><<<gblocks, 256, 0, stream>>>(vbf,  wup_bf,              b_up,  actA, Mpad);
    gemm_kernel<OUT_EMB, true><<<gblocks, 256, 0, stream>>>(actA, wsl_bf + 0 * OUT_EMB * OUT_EMB, bs + 0 * OUT_EMB, actB, Mpad);
    gemm_kernel<OUT_EMB, true><<<gblocks, 256, 0, stream>>>(actB, wsl_bf + 1 * OUT_EMB * OUT_EMB, bs + 1 * OUT_EMB, actA, Mpad);
    gemm_kernel<OUT_EMB, true><<<gblocks, 256, 0, stream>>>(actA, wsl_bf + 2 * OUT_EMB * OUT_EMB, bs + 2 * OUT_EMB, actB, Mpad);

    out_kernel<<<(M * 4 + 255) / 256, 256, 0, stream>>>(actB, W_out, (float*)d_out, M);
}

// Round 5
// 849.189 us; speedup vs baseline: 1.1287x; 1.1287x over previous
//
#include <hip/hip_runtime.h>

#define HIDDEN 128
#define OUT_EMB 256
#define NLAYERS 3
#define TM 64
#define LDA 264   // LDS row stride in bf16 elements (256 + 8 pad)

typedef __bf16 bf16x8 __attribute__((ext_vector_type(8)));
typedef float f32x4 __attribute__((ext_vector_type(4)));

__device__ __forceinline__ unsigned short f2bf(float x) {
    union { float f; unsigned u; } c; c.f = x;
    unsigned r = c.u + 0x7fff + ((c.u >> 16) & 1);
    return (unsigned short)(r >> 16);
}
__device__ __forceinline__ float bf2f(unsigned short h) {
    union { unsigned u; float f; } c; c.u = ((unsigned)h) << 16;
    return c.f;
}
__device__ __forceinline__ unsigned pack2(float a, float b) {
    return (unsigned)f2bf(a) | ((unsigned)f2bf(b) << 16);
}

// ---------------- hist + weight convert (grid-stitched) ----------------
__global__ __launch_bounds__(256) void hist_convert_kernel(
    const int* __restrict__ idx, int* __restrict__ counts, int ne, int nbh,
    const float* __restrict__ wup_f, const float* __restrict__ ws_f,
    unsigned short* __restrict__ wup, unsigned short* __restrict__ wsl)
{
    if ((int)blockIdx.x < nbh) {
        int e = blockIdx.x * 256 + threadIdx.x;
        if (e < ne) atomicAdd(&counts[idx[e]], 1);
    } else {
        const int n1 = OUT_EMB * HIDDEN;             // 32768 (div by 4)
        const int n2 = NLAYERS * OUT_EMB * OUT_EMB;  // 196608
        int t = (blockIdx.x - nbh) * 256 + threadIdx.x;
        int base = t * 4;
        if (base < n1) {
            f32x4 x = *(const f32x4*)(wup_f + base);
            uint2 p; p.x = pack2(x[0], x[1]); p.y = pack2(x[2], x[3]);
            *(uint2*)(wup + base) = p;
        } else if (base < n1 + n2) {
            int j = base - n1;
            f32x4 x = *(const f32x4*)(ws_f + j);
            uint2 p; p.x = pack2(x[0], x[1]); p.y = pack2(x[2], x[3]);
            *(uint2*)(wsl + j) = p;
        }
    }
}

// ---------------- parallel exclusive scan ----------------
__global__ __launch_bounds__(256) void scan1_kernel(
    const int* __restrict__ counts, int* __restrict__ bsum, int n)
{
    __shared__ int sh[256];
    int t = threadIdx.x;
    int i = blockIdx.x * 256 + t;
    sh[t] = (i < n) ? counts[i] : 0;
    __syncthreads();
    for (int off = 128; off > 0; off >>= 1) {
        if (t < off) sh[t] += sh[t + off];
        __syncthreads();
    }
    if (t == 0) bsum[blockIdx.x] = sh[0];
}

__global__ __launch_bounds__(256) void scan2_kernel(
    int* __restrict__ bsum, int* __restrict__ boff, int nb)
{
    __shared__ int sh[256];
    int t = threadIdx.x;
    int v = (t < nb) ? bsum[t] : 0;
    sh[t] = v;
    __syncthreads();
    for (int off = 1; off < 256; off <<= 1) {
        int u = (t >= off) ? sh[t - off] : 0;
        __syncthreads();
        sh[t] += u;
        __syncthreads();
    }
    if (t < nb) boff[t] = sh[t] - v;
}

__global__ __launch_bounds__(256) void scan3_kernel(
    const int* __restrict__ counts, const int* __restrict__ boff,
    int* __restrict__ offsets, int* __restrict__ cursor, int n)
{
    __shared__ int sh[256];
    int t = threadIdx.x;
    int i = blockIdx.x * 256 + t;
    int v = (i < n) ? counts[i] : 0;
    sh[t] = v;
    __syncthreads();
    for (int off = 1; off < 256; off <<= 1) {
        int u = (t >= off) ? sh[t - off] : 0;
        __syncthreads();
        sh[t] += u;
        __syncthreads();
    }
    if (i < n) {
        int excl = boff[blockIdx.x] + sh[t] - v;
        offsets[i] = excl;
        cursor[i]  = excl;
    }
}

__global__ __launch_bounds__(256) void fill_kernel(
    const int* __restrict__ idx, int* __restrict__ cursor,
    int* __restrict__ edge_list, int ne)
{
    int e = blockIdx.x * 256 + threadIdx.x;
    if (e < ne) {
        int pos = atomicAdd(&cursor[idx[e]], 1);
        edge_list[pos] = e;
    }
}

// ---------------- gather-reduce (R3 structure + nontemporal e2 loads) ----------------
__global__ __launch_bounds__(256) void gather_kernel(
    const float* __restrict__ e2, const int* __restrict__ edge_list,
    const int* __restrict__ offsets, const int* __restrict__ counts,
    unsigned short* __restrict__ vbf, int Mpad)
{
    int node = blockIdx.x * 4 + (threadIdx.x >> 6);
    if (node >= Mpad) return;
    int lane = threadIdx.x & 63;
    int half = lane >> 5;
    int c4   = lane & 31;
    int start = offsets[node];
    int cnt   = counts[node];

    f32x4 a0 = {0.f, 0.f, 0.f, 0.f};
    f32x4 a1 = {0.f, 0.f, 0.f, 0.f};

    int j = 0;
    for (; j + 4 <= cnt; j += 4) {
        int e0 = edge_list[start + j + half];
        int e1 = edge_list[start + j + 2 + half];
        f32x4 x0 = __builtin_nontemporal_load((const f32x4*)(e2 + (long long)e0 * HIDDEN + c4 * 4));
        f32x4 x1 = __builtin_nontemporal_load((const f32x4*)(e2 + (long long)e1 * HIDDEN + c4 * 4));
        a0 += x0;
        a1 += x1;
    }
    for (; j + 2 <= cnt; j += 2) {
        int e0 = edge_list[start + j + half];
        f32x4 x0 = __builtin_nontemporal_load((const f32x4*)(e2 + (long long)e0 * HIDDEN + c4 * 4));
        a0 += x0;
    }
    if (j < cnt && half == 0) {
        int e0 = edge_list[start + j];
        f32x4 x0 = __builtin_nontemporal_load((const f32x4*)(e2 + (long long)e0 * HIDDEN + c4 * 4));
        a1 += x0;
    }
    a0 += a1;
    a0[0] += __shfl_xor(a0[0], 32);
    a0[1] += __shfl_xor(a0[1], 32);
    a0[2] += __shfl_xor(a0[2], 32);
    a0[3] += __shfl_xor(a0[3], 32);

    if (half == 0) {
        uint2 p; p.x = pack2(a0[0], a0[1]); p.y = pack2(a0[2], a0[3]);
        *(uint2*)(vbf + (long long)node * HIDDEN + c4 * 4) = p;
    }
}

// ---------------- fused MLP, operand-swapped MFMA ----------------
// wave wv owns cols [wv*64, wv*64+64). MFMA: A-op = weights, B-op = act.
// D layout: col(lane&15) = m, row(kq*4+r) = n  -> epilogue writes 4 consecutive
// n at fixed m: one 8B ds_write per tile instead of 4 scalar 2B writes.
__global__ __launch_bounds__(256) void mlp_kernel(
    const unsigned short* __restrict__ vbf,   // [Mpad][128] bf16
    const unsigned short* __restrict__ wup,   // [256][128] bf16
    const float* __restrict__ bup,            // [256]
    const unsigned short* __restrict__ wsl,   // [3][256][256] bf16
    const float* __restrict__ bs,             // [3][256]
    const float* __restrict__ wout,           // [256] fp32
    float* __restrict__ out, int M)
{
    __shared__ unsigned short act[TM * LDA];

    const int tid  = threadIdx.x;
    const int wv   = tid >> 6;
    const int lane = tid & 63;
    const int ln15 = lane & 15;
    const int kq   = lane >> 4;          // 0..3
    const int n0   = wv * 64;
    const long long rowbase = (long long)blockIdx.x * TM;

    f32x4 acc[4][4];

    // ---- up-proj: K=128; A-op = wup rows (n), B-op = vbf rows (m), both global ----
    #pragma unroll
    for (int mt = 0; mt < 4; ++mt)
        #pragma unroll
        for (int nt = 0; nt < 4; ++nt)
            acc[mt][nt] = (f32x4){0.f, 0.f, 0.f, 0.f};

    #pragma unroll
    for (int ks = 0; ks < 4; ++ks) {
        bf16x8 a[4], w[4];
        #pragma unroll
        for (int mt = 0; mt < 4; ++mt)
            a[mt] = *(const bf16x8*)&vbf[(rowbase + mt * 16 + ln15) * HIDDEN + ks * 32 + kq * 8];
        #pragma unroll
        for (int nt = 0; nt < 4; ++nt)
            w[nt] = *(const bf16x8*)&wup[(n0 + nt * 16 + ln15) * HIDDEN + ks * 32 + kq * 8];
        #pragma unroll
        for (int mt = 0; mt < 4; ++mt)
            #pragma unroll
            for (int nt = 0; nt < 4; ++nt)
                acc[mt][nt] = __builtin_amdgcn_mfma_f32_16x16x32_bf16(w[nt], a[mt], acc[mt][nt], 0, 0, 0);
    }
    #pragma unroll
    for (int nt = 0; nt < 4; ++nt) {
        int nb4 = n0 + nt * 16 + kq * 4;          // 4 consecutive n for regs r=0..3
        f32x4 bi = *(const f32x4*)(bup + nb4);
        #pragma unroll
        for (int mt = 0; mt < 4; ++mt) {
            int row = mt * 16 + ln15;             // m = col = lane&15
            float x0 = acc[mt][nt][0] + bi[0];
            float x1 = acc[mt][nt][1] + bi[1];
            float x2 = acc[mt][nt][2] + bi[2];
            float x3 = acc[mt][nt][3] + bi[3];
            uint2 p; p.x = pack2(x0, x1); p.y = pack2(x2, x3);
            *(uint2*)&act[row * LDA + nb4] = p;
        }
    }
    __syncthreads();

    // ---- 3 hidden layers: K=256, bias + SiLU ----
    for (int l = 0; l < NLAYERS; ++l) {
        const unsigned short* W = wsl + l * OUT_EMB * OUT_EMB;
        const float* bias_l = bs + l * OUT_EMB;

        #pragma unroll
        for (int mt = 0; mt < 4; ++mt)
            #pragma unroll
            for (int nt = 0; nt < 4; ++nt)
                acc[mt][nt] = (f32x4){0.f, 0.f, 0.f, 0.f};

        #pragma unroll
        for (int ks = 0; ks < 8; ++ks) {
            bf16x8 a[4], w[4];
            #pragma unroll
            for (int mt = 0; mt < 4; ++mt)
                a[mt] = *(const bf16x8*)&act[(mt * 16 + ln15) * LDA + ks * 32 + kq * 8];
            #pragma unroll
            for (int nt = 0; nt < 4; ++nt)
                w[nt] = *(const bf16x8*)&W[(n0 + nt * 16 + ln15) * OUT_EMB + ks * 32 + kq * 8];
            #pragma unroll
            for (int mt = 0; mt < 4; ++mt)
                #pragma unroll
                for (int nt = 0; nt < 4; ++nt)
                    acc[mt][nt] = __builtin_amdgcn_mfma_f32_16x16x32_bf16(w[nt], a[mt], acc[mt][nt], 0, 0, 0);
        }
        __syncthreads();   // all LDS reads done before overwrite
        #pragma unroll
        for (int nt = 0; nt < 4; ++nt) {
            int nb4 = n0 + nt * 16 + kq * 4;
            f32x4 bi = *(const f32x4*)(bias_l + nb4);
            #pragma unroll
            for (int mt = 0; mt < 4; ++mt) {
                int row = mt * 16 + ln15;
                float x0 = acc[mt][nt][0] + bi[0];
                float x1 = acc[mt][nt][1] + bi[1];
                float x2 = acc[mt][nt][2] + bi[2];
                float x3 = acc[mt][nt][3] + bi[3];
                x0 = x0 / (1.f + __expf(-x0));
                x1 = x1 / (1.f + __expf(-x1));
                x2 = x2 / (1.f + __expf(-x2));
                x3 = x3 / (1.f + __expf(-x3));
                uint2 p; p.x = pack2(x0, x1); p.y = pack2(x2, x3);
                *(uint2*)&act[row * LDA + nb4] = p;
            }
        }
        __syncthreads();
    }

    // ---- output: out[m] = act[m] . wout ; 4 lanes per row ----
    {
        int r = tid >> 2;
        int part = tid & 3;
        const unsigned short* arow = &act[r * LDA + part * 64];
        const float* wrow = wout + part * 64;
        float s = 0.f;
        #pragma unroll
        for (int jj = 0; jj < 64; ++jj) s += bf2f(arow[jj]) * wrow[jj];
        s += __shfl_xor(s, 1);
        s += __shfl_xor(s, 2);
        long long rowg = rowbase + r;
        if (part == 0 && rowg < M) out[rowg] = s;
    }
}

extern "C" void kernel_launch(void* const* d_in, const int* in_sizes, int n_in,
                              void* d_out, int out_size, void* d_ws, size_t ws_size,
                              hipStream_t stream) {
    const float* e2    = (const float*)d_in[0];
    const int*   idx   = (const int*)d_in[1];
    const float* W_up  = (const float*)d_in[2];
    const float* b_up  = (const float*)d_in[3];
    const float* Ws    = (const float*)d_in[4];
    const float* bs    = (const float*)d_in[5];
    const float* W_out = (const float*)d_in[6];

    const int ne = in_sizes[0] / HIDDEN;
    const int M  = out_size;                      // 50000
    const int Mpad = ((M + TM - 1) / TM) * TM;    // 50048
    const int nb = (Mpad + 255) / 256;            // 196

    char* p = (char*)d_ws;
    unsigned short* vbf    = (unsigned short*)p;  p += (size_t)Mpad * HIDDEN * 2;
    unsigned short* wup_bf = (unsigned short*)p;  p += (size_t)OUT_EMB * HIDDEN * 2;
    unsigned short* wsl_bf = (unsigned short*)p;  p += (size_t)NLAYERS * OUT_EMB * OUT_EMB * 2;
    int* counts    = (int*)p;  p += (size_t)Mpad * 4;
    int* offsets   = (int*)p;  p += (size_t)Mpad * 4;
    int* cursor    = (int*)p;  p += (size_t)Mpad * 4;
    int* bsum      = (int*)p;  p += 256 * 4;
    int* boff      = (int*)p;  p += 256 * 4;
    int* edge_list = (int*)p;  p += (size_t)ne * 4;

    hipMemsetAsync(counts, 0, (size_t)Mpad * 4, stream);

    {
        const int nbh = (ne + 255) / 256;
        const int total4 = (OUT_EMB * HIDDEN + NLAYERS * OUT_EMB * OUT_EMB) / 4;
        const int nbc = (total4 + 255) / 256;
        hist_convert_kernel<<<nbh + nbc, 256, 0, stream>>>(
            idx, counts, ne, nbh, W_up, Ws, wup_bf, wsl_bf);
    }
    scan1_kernel<<<nb, 256, 0, stream>>>(counts, bsum, Mpad);
    scan2_kernel<<<1, 256, 0, stream>>>(bsum, boff, nb);
    scan3_kernel<<<nb, 256, 0, stream>>>(counts, boff, offsets, cursor, Mpad);
    fill_kernel <<<(ne + 255) / 256, 256, 0, stream>>>(idx, cursor, edge_list, ne);

    gather_kernel<<<(Mpad + 3) / 4, 256, 0, stream>>>(e2, edge_list, offsets, counts, vbf, Mpad);

    mlp_kernel<<<Mpad / TM, 256, 0, stream>>>(vbf, wup_bf, b_up, wsl_bf, bs, W_out,
                                              (float*)d_out, M);
}